// Round 1
// baseline (452.333 us; speedup 1.0000x reference)
//
#include <hip/hip_runtime.h>

#define B_   512
#define C_   256
#define HWD_ 384

typedef __bf16 bf16x8 __attribute__((ext_vector_type(8)));
typedef __bf16 bf16x4 __attribute__((ext_vector_type(4)));
typedef float  f32x4  __attribute__((ext_vector_type(4)));

// chunk swizzle: physical 16B-chunk = logical ^ CSWZ(row). Same formula at every
// writer (K1 phaseB, K2) and reader (K3 frag loads). Involutive XOR.
#define CSWZ(r) ((((r) ^ ((r) >> 2))) & 3)

__device__ __forceinline__ void gload16(const void* g, void* l) {
    __builtin_amdgcn_global_load_lds((const __attribute__((address_space(1))) void*)g,
                                     (__attribute__((address_space(3))) void*)l, 16, 0, 0);
}

// =====================================================================
// K1: per-(b,c) mean  +  fea -> bf16, transposed to feaT[b][n][j] with
// the GEMM's LDS chunk-swizzle baked into the global layout.
// block = (jb, b): rows j0..j0+63, all n (deterministic in-block mean).
// =====================================================================
__global__ __launch_bounds__(256) void prep_kernel(const float* __restrict__ x,
                                                   float* __restrict__ cadj,
                                                   __bf16* __restrict__ feaT) {
    const int jb = blockIdx.x, b = blockIdx.y;
    const int j0 = jb * 64;
    __shared__ __bf16 LT[384][68];   // [n][j], row 136B: phaseA writes 2-way, phaseB reads 4-way

    const int t = threadIdx.x;
    // ---- phase A: coalesced read, row-sum, scatter bf16 into LT[n][j] ----
    {
        const int j = t >> 2, seg = t & 3;
        const float4* xp = (const float4*)(x + (size_t)(b * C_ + j0 + j) * HWD_);
        float sum = 0.f;
#pragma unroll
        for (int u = 0; u < 24; ++u) {
            const int n4 = u * 4 + seg;          // interleaved segs: spreads LDS banks
            float4 v = xp[n4];
            sum += (v.x + v.y) + (v.z + v.w);
            const int n = n4 * 4;
            LT[n + 0][j] = (__bf16)v.x;
            LT[n + 1][j] = (__bf16)v.y;
            LT[n + 2][j] = (__bf16)v.z;
            LT[n + 3][j] = (__bf16)v.w;
        }
        sum += __shfl_xor(sum, 1, 64);           // lanes 4j+seg share j
        sum += __shfl_xor(sum, 2, 64);
        if (seg == 0) cadj[b * C_ + j0 + j] = sum * (1.0f / HWD_);
    }
    __syncthreads();
    // ---- phase B: LT[n][4k..4k+3] -> feaT row n, swizzled chunk position ----
    {
        const int k  = t & 15;                   // j-quad index within 64-j slice
        const int qq = t >> 4;                   // 16 n per iteration
        const int kbg = jb * 2 + (k >> 3);       // global 32-j block within 256-j row
        const int cl  = (k >> 1) & 3;            // logical 16B chunk in block
        const int sub = k & 1;                   // 8B half of chunk
        char* fb = (char*)feaT + (size_t)(b * HWD_) * 512;
#pragma unroll
        for (int it = 0; it < 24; ++it) {
            const int n = it * 16 + qq;
            bf16x4 v = *(const bf16x4*)&LT[n][k * 4];
            const int off = kbg * 64 + ((cl ^ CSWZ(n)) << 4) + sub * 8;
            *(bf16x4*)(fb + (size_t)n * 512 + off) = v;
        }
    }
}

// =====================================================================
// K2: A_b[i][j] = bf16( adj[i][j] * 2*sigmoid(-|ca_j - ca_i|) ), swizzled layout.
// block = (ib, b): 64 rows of i; wave reads full 256-f32 adj rows coalesced.
// =====================================================================
__global__ __launch_bounds__(256) void amat_kernel(const float* __restrict__ adj,
                                                   const float* __restrict__ cadj,
                                                   __bf16* __restrict__ Abf) {
    const int ib = blockIdx.x, b = blockIdx.y;
    const int i0 = ib * 64;
    __shared__ float ca_s[C_];
    const int t = threadIdx.x;
    ca_s[t] = cadj[b * C_ + t];
    __syncthreads();

    const int w = t >> 6, l = t & 63;
    const int kb = l >> 3, cl = (l >> 1) & 3, sub = l & 1;
    const float4 cav = ((const float4*)ca_s)[l];
    const float* cvp = (const float*)&cav;
    char* ab = (char*)Abf + (size_t)(b * C_) * 512;
#pragma unroll
    for (int itr = 0; itr < 16; ++itr) {
        const int i = i0 + w + itr * 4;
        const float ca_i = ca_s[i];
        float4 av = ((const float4*)(adj + (size_t)i * C_))[l];   // j = 4l..4l+3
        const float* avp = (const float*)&av;
        bf16x4 pk;
#pragma unroll
        for (int e = 0; e < 4; ++e) {
            float d = cvp[e] - ca_i;
            float tt = __expf(-fabsf(d));
            float s = 2.f * tt / (1.f + tt);
            pk[e] = (__bf16)(avp[e] * s);
        }
        const int off = kb * 64 + ((cl ^ CSWZ(i)) << 4) + sub * 8;
        *(bf16x4*)(ab + (size_t)i * 512 + off) = pk;
    }
}

// =====================================================================
// K3: out[b] = relu( (A_b @ fea_b) * para ). 128x128 tile, K-step 32,
// both operands staged with global_load_lds width-16 into linear LDS;
// frag ds_read_b128 applies the XOR swizzle (≈2-way banks, free).
// =====================================================================
__global__ __launch_bounds__(256) void gemm_kernel(const __bf16* __restrict__ Abf,
                                                   const __bf16* __restrict__ feaT,
                                                   const float* __restrict__ para,
                                                   float* __restrict__ out) {
    const int mt = blockIdx.x, nt = blockIdx.y, b = blockIdx.z;
    const int i0 = mt * 128, n0 = nt * 128;
    __shared__ __bf16 As[128 * 32];
    __shared__ __bf16 Bs[128 * 32];

    const int tid = threadIdx.x, lane = tid & 63, w = tid >> 6;
    const int wm = w & 1, wn = w >> 1, lm = lane & 15, quad = lane >> 4;

    const char* gA = (const char*)Abf + (size_t)(b * C_ + i0) * 512;
    const char* gB = (const char*)feaT + (size_t)(b * HWD_ + n0) * 512;

    // staging chunk coords: rr=0 -> chunk tid, rr=1 -> chunk tid+256
    const int r0 = tid >> 2, c16 = (tid & 3) * 16;
    char* ldsA0 = (char*)As + (size_t)(w * 64) * 16;
    char* ldsA1 = (char*)As + (size_t)(w * 64 + 256) * 16;
    char* ldsB0 = (char*)Bs + (size_t)(w * 64) * 16;
    char* ldsB1 = (char*)Bs + (size_t)(w * 64 + 256) * 16;

    f32x4 acc[4][4];
#pragma unroll
    for (int mm = 0; mm < 4; ++mm)
#pragma unroll
        for (int nn = 0; nn < 4; ++nn)
            acc[mm][nn] = (f32x4){0.f, 0.f, 0.f, 0.f};

    for (int k0 = 0; k0 < C_; k0 += 32) {
        const int kb64 = (k0 >> 5) * 64;
        __syncthreads();                                  // prior frag reads done
        gload16(gA + (size_t)r0 * 512 + kb64 + c16,        ldsA0);
        gload16(gA + (size_t)(r0 + 64) * 512 + kb64 + c16, ldsA1);
        gload16(gB + (size_t)r0 * 512 + kb64 + c16,        ldsB0);
        gload16(gB + (size_t)(r0 + 64) * 512 + kb64 + c16, ldsB1);
        __syncthreads();                                  // compiler drains vmcnt(0) here

        bf16x8 af[4], bfr[4];
#pragma unroll
        for (int mm = 0; mm < 4; ++mm) {
            const int ra = wm * 64 + mm * 16 + lm;
            af[mm] = *(const bf16x8*)((const char*)As + ra * 64 + ((quad ^ CSWZ(ra)) << 4));
        }
#pragma unroll
        for (int nn = 0; nn < 4; ++nn) {
            const int rb = wn * 64 + nn * 16 + lm;
            bfr[nn] = *(const bf16x8*)((const char*)Bs + rb * 64 + ((quad ^ CSWZ(rb)) << 4));
        }
#pragma unroll
        for (int mm = 0; mm < 4; ++mm)
#pragma unroll
            for (int nn = 0; nn < 4; ++nn)
                acc[mm][nn] = __builtin_amdgcn_mfma_f32_16x16x32_bf16(
                    af[mm], bfr[nn], acc[mm][nn], 0, 0, 0);
    }

    // epilogue: *para, relu, store (mapping identical to verified baseline)
#pragma unroll
    for (int mm = 0; mm < 4; ++mm) {
#pragma unroll
        for (int r = 0; r < 4; ++r) {
            const int i = i0 + wm * 64 + mm * 16 + quad * 4 + r;
            const float* pp = para + (size_t)i * HWD_;
            float* op = out + ((size_t)b * C_ + i) * HWD_;
#pragma unroll
            for (int nn = 0; nn < 4; ++nn) {
                const int n = n0 + wn * 64 + nn * 16 + lm;
                float v = acc[mm][nn][r] * pp[n];
                op[n] = v > 0.f ? v : 0.f;
            }
        }
    }
}

// =====================================================================
// Fallback path (verified baseline, 432.6us) if workspace is too small.
// =====================================================================
__global__ __launch_bounds__(256) void mean_kernel(const float* __restrict__ x,
                                                   float* __restrict__ cadj) {
    const int row  = (blockIdx.x << 2) + (threadIdx.x >> 6);
    const int lane = threadIdx.x & 63;
    const float2* p = (const float2*)(x + (size_t)row * HWD_);
    float s = 0.f;
#pragma unroll
    for (int t = 0; t < 3; ++t) {
        float2 v = p[lane + (t << 6)];
        s += v.x + v.y;
    }
#pragma unroll
    for (int off = 32; off; off >>= 1) s += __shfl_xor(s, off, 64);
    if (lane == 0) cadj[row] = s * (1.0f / HWD_);
}

__global__ __launch_bounds__(256) void gemm_fb(const float* __restrict__ x,
                                               const float* __restrict__ adj,
                                               const float* __restrict__ para,
                                               const float* __restrict__ cadj,
                                               float* __restrict__ out) {
    const int mt = blockIdx.x;
    const int nt = blockIdx.y;
    const int b  = blockIdx.z;
    const int i0 = mt * 128;
    const int n0 = nt * 128;

    __shared__ __bf16 As[128][40];
    __shared__ __bf16 Bs[128][40];

    const int tid  = threadIdx.x;
    const int lane = tid & 63;
    const int w    = tid >> 6;
    const int wm   = w & 1, wn = w >> 1;
    const int lm   = lane & 15, quad = lane >> 4;

    const float* ca = cadj + b * C_;
    const int a_row  = tid >> 1;
    const int a_half = tid & 1;
    const float ca_i = ca[i0 + a_row];
    const int b_n  = tid & 127;
    const int b_jg = tid >> 7;

    f32x4 acc[4][4];
#pragma unroll
    for (int mm = 0; mm < 4; ++mm)
#pragma unroll
        for (int nn = 0; nn < 4; ++nn)
            acc[mm][nn] = (f32x4){0.f, 0.f, 0.f, 0.f};

    for (int k0 = 0; k0 < C_; k0 += 32) {
        __syncthreads();
        {
            const float* ap = adj + (size_t)(i0 + a_row) * C_ + k0 + a_half * 16;
            float4 av[4];
#pragma unroll
            for (int q = 0; q < 4; ++q) av[q] = ((const float4*)ap)[q];
            bf16x8 pk0, pk1;
#pragma unroll
            for (int jj = 0; jj < 16; ++jj) {
                float aval = ((const float*)av)[jj];
                float d = ca[k0 + a_half * 16 + jj] - ca_i;
                float t = __expf(-fabsf(d));
                float s = 2.f * t / (1.f + t);
                float v = aval * s;
                if (jj < 8) pk0[jj & 7] = (__bf16)v;
                else        pk1[jj & 7] = (__bf16)v;
            }
            *(bf16x8*)&As[a_row][a_half * 16]     = pk0;
            *(bf16x8*)&As[a_row][a_half * 16 + 8] = pk1;
        }
        {
            const float* xp = x + (size_t)(b * C_ + k0 + b_jg * 16) * HWD_ + n0 + b_n;
            bf16x8 pk0, pk1;
#pragma unroll
            for (int jj = 0; jj < 16; ++jj) {
                float v = xp[(size_t)jj * HWD_];
                if (jj < 8) pk0[jj & 7] = (__bf16)v;
                else        pk1[jj & 7] = (__bf16)v;
            }
            *(bf16x8*)&Bs[b_n][b_jg * 16]     = pk0;
            *(bf16x8*)&Bs[b_n][b_jg * 16 + 8] = pk1;
        }
        __syncthreads();
        bf16x8 af[4], bfr[4];
#pragma unroll
        for (int mm = 0; mm < 4; ++mm)
            af[mm] = *(const bf16x8*)&As[wm * 64 + mm * 16 + lm][quad * 8];
#pragma unroll
        for (int nn = 0; nn < 4; ++nn)
            bfr[nn] = *(const bf16x8*)&Bs[wn * 64 + nn * 16 + lm][quad * 8];
#pragma unroll
        for (int mm = 0; mm < 4; ++mm)
#pragma unroll
            for (int nn = 0; nn < 4; ++nn)
                acc[mm][nn] = __builtin_amdgcn_mfma_f32_16x16x32_bf16(
                    af[mm], bfr[nn], acc[mm][nn], 0, 0, 0);
    }

#pragma unroll
    for (int mm = 0; mm < 4; ++mm) {
#pragma unroll
        for (int r = 0; r < 4; ++r) {
            const int i = i0 + wm * 64 + mm * 16 + quad * 4 + r;
            const float* pp = para + (size_t)i * HWD_;
            float* op = out + ((size_t)b * C_ + i) * HWD_;
#pragma unroll
            for (int nn = 0; nn < 4; ++nn) {
                const int n = n0 + wn * 64 + nn * 16 + lm;
                float v = acc[mm][nn][r] * pp[n];
                op[n] = v > 0.f ? v : 0.f;
            }
        }
    }
}

extern "C" void kernel_launch(void* const* d_in, const int* in_sizes, int n_in,
                              void* d_out, int out_size, void* d_ws, size_t ws_size,
                              hipStream_t stream) {
    const float* x    = (const float*)d_in[0];
    const float* adj  = (const float*)d_in[1];
    const float* para = (const float*)d_in[2];
    float* out  = (float*)d_out;
    float* cadj = (float*)d_ws;                       // 512*256 f32 = 512 KB

    const size_t CADJ_B = 524288ull;
    const size_t ABF_B  = 67108864ull;                // 512*256*256 bf16 = 64 MB
    const size_t FEAT_B = 100663296ull;               // 512*384*256 bf16 = 96 MB
    if (ws_size >= CADJ_B + ABF_B + FEAT_B) {
        __bf16* Abf  = (__bf16*)((char*)d_ws + CADJ_B);
        __bf16* feaT = (__bf16*)((char*)d_ws + CADJ_B + ABF_B);
        prep_kernel<<<dim3(4, B_), 256, 0, stream>>>(x, cadj, feaT);
        amat_kernel<<<dim3(4, B_), 256, 0, stream>>>(adj, cadj, Abf);
        gemm_kernel<<<dim3(2, 3, B_), 256, 0, stream>>>(Abf, feaT, para, out);
    } else {
        mean_kernel<<<dim3((B_ * C_) / 4), 256, 0, stream>>>(x, cadj);
        gemm_fb<<<dim3(2, 3, B_), 256, 0, stream>>>(x, adj, para, cadj, out);
    }
}